// Round 10
// baseline (119.895 us; speedup 1.0000x reference)
//
#include <hip/hip_runtime.h>
#include <math.h>

#define R_ROUTES 1152
#define N_CAPS 10
#define C_IN 8
#define D_DIM 16
#define B_BATCH 128
#define JD 160                      // N_CAPS * D_DIM
#define KK 9216                     // R_ROUTES * C_IN (GEMM K)
#define KSPLIT 48                   // 24 routes = 192 k per split
#define RS 24                       // routes per k-split
#define NG 5                        // jd groups of 32
#define SELEM (B_BATCH * JD)        // 20480 floats per s copy
#define NSHADOW 2                   // atomic-contention shadows per iteration

typedef __attribute__((ext_vector_type(8))) short short8;   // 8 bf16 (4 VGPRs)
typedef __attribute__((ext_vector_type(4))) float f32x4;    // MFMA accumulator

__device__ inline unsigned short f2bf(float f) {            // RNE fp32 -> bf16
    unsigned int u = __float_as_uint(f);
    unsigned int r = u + 0x7FFFu + ((u >> 16) & 1u);
    return (unsigned short)(r >> 16);
}
__device__ inline float bf2f(unsigned short h) {
    return __uint_as_float(((unsigned int)h) << 16);
}

// ---------------------------------------------------------------------------
// ws layout (byte offsets):
//   b_ij  fp32 [1152][10]         @ 0        (46080 B)
//   s_all fp32 [3][2][128][160]   @ 46080    (491520 B; iter-major, shadow-minor)
//   xh    bf16 [128][9216]        @ 537600   A-layout [b][k]
//   xl    bf16 [128][9216]        @ 2896896
//   xT    bf16 [9216][128]        @ 5256192  A-layout for k_va ([rc][b])
// Lesson log:
//  R5/R6: in-kernel grid barriers ~20us each (agent-scope inv/wb) -> multi-dispatch.
//  R7 (113.4us): atomic split-K into s + fused squash/agree, KSPLIT=48.
//  R8 (152us REGRESSION): 96-way atomic contention + 2x k_va s-traffic +
//    fence epilogue (multi-variable; contention prime suspect, ~linear cost).
//  R9 (112.4us): W-lo MFMA term dropped -> NEUTRAL => k_iter not compute-bound.
//    Budget residual ~7us/iter unexplained => atomic serialization hypothesis.
//  R10: single variable -- NSHADOW=2 halves per-address contention (48->24).
// ---------------------------------------------------------------------------

// prep: x -> bf16 hi/lo + transpose; zero b_ij and all 6 s shadows
__global__ __launch_bounds__(256) void k_prep(
    const float* __restrict__ x, unsigned short* __restrict__ xh,
    unsigned short* __restrict__ xl, unsigned short* __restrict__ xT,
    float* __restrict__ b_ij, float* __restrict__ s_all) {
    __shared__ float tile[32][33];
    int bx = blockIdx.x;            // rc tile 0..287
    int by = blockIdx.y;            // b tile 0..3
    int t = threadIdx.x;
    int tx = t & 31, ty = t >> 5;
#pragma unroll
    for (int i = 0; i < 4; i++) {
        int row = ty + i * 8;       // b_local
        size_t idx = (size_t)(by * 32 + row) * KK + bx * 32 + tx;
        float v = x[idx];
        tile[row][tx] = v;
        unsigned short hi = f2bf(v);
        xh[idx] = hi;
        xl[idx] = f2bf(v - bf2f(hi));
    }
    __syncthreads();
#pragma unroll
    for (int i = 0; i < 4; i++) {
        int row = ty + i * 8;       // rc_local
        xT[(size_t)(bx * 32 + row) * B_BATCH + by * 32 + tx] = f2bf(tile[tx][row]);
    }
    int bid = by * 288 + bx;        // 0..1151
    if (bid < 480) s_all[bid * 256 + t] = 0.f;              // 480*256 == 6*20480
    else if (bid < 525) b_ij[(bid - 480) * 256 + t] = 0.f;  // 45*256 == 11520
}

// Fused GEMM iteration: softmax(b_ij) -> c, stage c*W-hi (bf16) in LDS,
// MFMA (ah*bh + al*bh) over this block's 192-k x 32-jd range, atomicAdd
// partials into shadow s[ks&1] (24-way per-address contention).
// Grid (48, 5), block 256.
template <bool FIRST>
__global__ __launch_bounds__(256) void k_iter(
    const unsigned short* __restrict__ xh, const unsigned short* __restrict__ xl,
    const float* __restrict__ W, const float* __restrict__ b_ij,
    float* __restrict__ s_pair) {
    __shared__ float cs[RS][N_CAPS];
    __shared__ unsigned short bhs[32][200];   // [jd_l][k_l], 400B rows (16B mult)
    int t = threadIdx.x;
    int ks = blockIdx.x, ng = blockIdx.y;
    int r0 = ks * RS, jd0 = ng * 32;
    float* s = s_pair + (ks & (NSHADOW - 1)) * SELEM;

    if (!FIRST && t < RS) {          // softmax for this block's routes
        float bj[N_CAPS], m = -1e30f;
#pragma unroll
        for (int j = 0; j < N_CAPS; j++) { bj[j] = b_ij[(r0 + t) * N_CAPS + j]; m = fmaxf(m, bj[j]); }
        float sum = 0.f;
#pragma unroll
        for (int j = 0; j < N_CAPS; j++) { bj[j] = expf(bj[j] - m); sum += bj[j]; }
        float inv = 1.f / sum;
#pragma unroll
        for (int j = 0; j < N_CAPS; j++) cs[t][j] = bj[j] * inv;
    }
    __syncthreads();

    // stage 24 routes x 32 jd of c*W hi: 768 pairs, 8 fp32 each
#pragma unroll
    for (int p = t; p < RS * 32; p += 256) {
        int rl = p >> 5, jdl = p & 31;
        const float* wp = W + ((size_t)(r0 + rl) * JD + jd0 + jdl) * C_IN;
        float c = FIRST ? 0.1f : cs[rl][(jd0 + jdl) >> 4];
        short8 vh;
#pragma unroll
        for (int i = 0; i < 8; i++) vh[i] = (short)f2bf(wp[i] * c);
        *(short8*)&bhs[jdl][rl * 8] = vh;    // k_local = rl*8+i
    }
    __syncthreads();

    int w = t >> 6, l = t & 63, row = l & 15, quad = l >> 4;
    const short8* pah0 = (const short8*)(xh + (size_t)(w * 16 + row) * KK + ks * 192);
    const short8* pal0 = (const short8*)(xl + (size_t)(w * 16 + row) * KK + ks * 192);
    const short8* pah1 = (const short8*)(xh + (size_t)((w + 4) * 16 + row) * KK + ks * 192);
    const short8* pal1 = (const short8*)(xl + (size_t)((w + 4) * 16 + row) * KK + ks * 192);
    f32x4 a00 = {0,0,0,0}, a01 = {0,0,0,0}, a10 = {0,0,0,0}, a11 = {0,0,0,0};
#pragma unroll
    for (int st = 0; st < 6; st++) {         // K = 192 = 6 steps of 32
        short8 Bh0 = *(const short8*)&bhs[row][st * 32 + quad * 8];
        short8 Bh1 = *(const short8*)&bhs[16 + row][st * 32 + quad * 8];
        short8 Ah0 = pah0[st * 4 + quad], Al0 = pal0[st * 4 + quad];
        short8 Ah1 = pah1[st * 4 + quad], Al1 = pal1[st * 4 + quad];
        a00 = __builtin_amdgcn_mfma_f32_16x16x32_bf16(Ah0, Bh0, a00, 0, 0, 0);
        a00 = __builtin_amdgcn_mfma_f32_16x16x32_bf16(Al0, Bh0, a00, 0, 0, 0);
        a01 = __builtin_amdgcn_mfma_f32_16x16x32_bf16(Ah0, Bh1, a01, 0, 0, 0);
        a01 = __builtin_amdgcn_mfma_f32_16x16x32_bf16(Al0, Bh1, a01, 0, 0, 0);
        a10 = __builtin_amdgcn_mfma_f32_16x16x32_bf16(Ah1, Bh0, a10, 0, 0, 0);
        a10 = __builtin_amdgcn_mfma_f32_16x16x32_bf16(Al1, Bh0, a10, 0, 0, 0);
        a11 = __builtin_amdgcn_mfma_f32_16x16x32_bf16(Ah1, Bh1, a11, 0, 0, 0);
        a11 = __builtin_amdgcn_mfma_f32_16x16x32_bf16(Al1, Bh1, a11, 0, 0, 0);
    }
#pragma unroll
    for (int i = 0; i < 4; i++) {            // C/D: col=lane&15 (jd), row=quad*4+i (b)
        int b0 = w * 16 + quad * 4 + i, b1 = b0 + 64;
        atomicAdd(&s[(size_t)b0 * JD + jd0 + row],      a00[i]);
        atomicAdd(&s[(size_t)b0 * JD + jd0 + 16 + row], a01[i]);
        atomicAdd(&s[(size_t)b1 * JD + jd0 + row],      a10[i]);
        atomicAdd(&s[(size_t)b1 * JD + jd0 + 16 + row], a11[i]);
    }
}

// Fused squash + agreement: read s shadows (2x80KB), squash -> v (bf16) in
// LDS, M2 tile (32 rc x 160 jd) via MFMA, b_ij update. Block owns 4 routes.
__global__ __launch_bounds__(256) void k_va(
    const unsigned short* __restrict__ xT, const float* __restrict__ s_pair,
    const float* __restrict__ W, float* __restrict__ b_ij) {
    __shared__ unsigned short vb[JD][136];   // [jd][b], +8 pad (272B, 16B-mult)
    __shared__ float m2[32][164];            // [rc_local][jd], +4 pad
    int t = threadIdx.x;
    int r0 = blockIdx.x * 4, rc0 = blockIdx.x * 32;

    // squash: 1280 (b,j) pairs, 5 per thread, 16 contiguous floats per shadow
#pragma unroll
    for (int q = 0; q < 5; q++) {
        int pi = t * 5 + q;                  // (b, j) pair
        int b = pi / N_CAPS, j = pi % N_CAPS;
        const float* sp0 = s_pair + (size_t)b * JD + j * D_DIM;
        const float* sp1 = sp0 + SELEM;
        float sv[D_DIM], sqn = 0.f;
#pragma unroll
        for (int d = 0; d < D_DIM; d++) {
            sv[d] = sp0[d] + sp1[d];
            sqn = fmaf(sv[d], sv[d], sqn);
        }
        float scale = sqn / ((1.f + sqn) * sqrtf(sqn));
#pragma unroll
        for (int d = 0; d < D_DIM; d++)
            vb[j * D_DIM + d][b] = f2bf(sv[d] * scale);
    }
    __syncthreads();

    int w = t >> 6, l = t & 63, row = l & 15, quad = l >> 4;
    for (int u = w; u < 20; u += 4) {        // 2 m-tiles x 10 n-tiles
        int mt = u / 10, nt = u % 10;
        const short8* pa = (const short8*)(xT + (size_t)(rc0 + mt * 16 + row) * B_BATCH);
        f32x4 acc = {0,0,0,0};
#pragma unroll
        for (int st = 0; st < 4; st++) {     // K = 128 = 4 steps of 32
            short8 Bv = *(const short8*)&vb[nt * 16 + row][st * 32 + quad * 8];
            acc = __builtin_amdgcn_mfma_f32_16x16x32_bf16(pa[st * 4 + quad], Bv, acc, 0, 0, 0);
        }
#pragma unroll
        for (int i = 0; i < 4; i++)          // C/D: col=jd, row=rc_local
            m2[mt * 16 + quad * 4 + i][nt * 16 + row] = acc[i];
    }
    __syncthreads();

    for (int p = t; p < 640; p += 256) {     // 4 routes x 160 jd
        int rl = p / JD, jd = p % JD;
        const float* wp = W + ((size_t)(r0 + rl) * JD + jd) * C_IN;
        float a = 0.f;
#pragma unroll
        for (int c = 0; c < C_IN; c++)
            a = fmaf(wp[c], m2[rl * 8 + c][jd], a);
#pragma unroll
        for (int off = 1; off < 16; off <<= 1) a += __shfl_xor(a, off, 16);
        if ((jd & 15) == 0)
            b_ij[(r0 + rl) * N_CAPS + (jd >> 4)] += a * (1.f / B_BATCH);
    }
}

// final: sum shadows + squash -> out
__global__ __launch_bounds__(320) void k_rs_final(
    const float* __restrict__ s_pair, float* __restrict__ out) {
    int t = threadIdx.x;                     // 320 = 2 b x 160 jd
    int bloc = t / JD, jd = t % JD;
    int b = blockIdx.x * 2 + bloc;
    size_t idx = (size_t)b * JD + jd;
    float acc = s_pair[idx] + s_pair[idx + SELEM];
    float sq = acc * acc;                    // lane%16 == jd%16 -> width-16 xor
#pragma unroll
    for (int off = 1; off < 16; off <<= 1) sq += __shfl_xor(sq, off, 16);
    float scale = sq / ((1.f + sq) * sqrtf(sq));
    out[idx] = acc * scale;
}

extern "C" void kernel_launch(void* const* d_in, const int* in_sizes, int n_in,
                              void* d_out, int out_size, void* d_ws, size_t ws_size,
                              hipStream_t stream) {
    const float* x = (const float*)d_in[0];   // [128,1152,8]
    const float* W = (const float*)d_in[1];   // [1,1152,10,16,8]
    float* out = (float*)d_out;               // [128,10,16,1]
    char* ws = (char*)d_ws;

    float*          b_ij = (float*)(ws + 0);
    float*          s_all = (float*)(ws + 46080);          // [3][2][20480]
    float*          s0 = s_all;
    float*          s1 = s_all + 2 * SELEM;
    float*          s2 = s_all + 4 * SELEM;
    unsigned short* xh   = (unsigned short*)(ws + 537600);
    unsigned short* xl   = (unsigned short*)(ws + 2896896);
    unsigned short* xT   = (unsigned short*)(ws + 5256192);

    k_prep<<<dim3(288, 4), 256, 0, stream>>>(x, xh, xl, xT, b_ij, s_all);

    k_iter<true><<<dim3(KSPLIT, NG), 256, 0, stream>>>(xh, xl, W, b_ij, s0);
    k_va<<<288, 256, 0, stream>>>(xT, s0, W, b_ij);

    k_iter<false><<<dim3(KSPLIT, NG), 256, 0, stream>>>(xh, xl, W, b_ij, s1);
    k_va<<<288, 256, 0, stream>>>(xT, s1, W, b_ij);

    k_iter<false><<<dim3(KSPLIT, NG), 256, 0, stream>>>(xh, xl, W, b_ij, s2);
    k_rs_final<<<64, 320, 0, stream>>>(s2, out);
}

// Round 11
// 115.258 us; speedup vs baseline: 1.0402x; 1.0402x over previous
//
#include <hip/hip_runtime.h>
#include <math.h>

#define R_ROUTES 1152
#define N_CAPS 10
#define C_IN 8
#define D_DIM 16
#define B_BATCH 128
#define JD 160                      // N_CAPS * D_DIM
#define KK 9216                     // R_ROUTES * C_IN (GEMM K)
#define KSPLIT 24                   // 48 routes = 384 k per split
#define RS 48                       // routes per k-split
#define NG 10                       // jd groups of 16 (one MFMA n-tile)

typedef __attribute__((ext_vector_type(8))) short short8;   // 8 bf16 (4 VGPRs)
typedef __attribute__((ext_vector_type(4))) float f32x4;    // MFMA accumulator

__device__ inline unsigned short f2bf(float f) {            // RNE fp32 -> bf16
    unsigned int u = __float_as_uint(f);
    unsigned int r = u + 0x7FFFu + ((u >> 16) & 1u);
    return (unsigned short)(r >> 16);
}
__device__ inline float bf2f(unsigned short h) {
    return __uint_as_float(((unsigned int)h) << 16);
}

// ---------------------------------------------------------------------------
// ws layout (byte offsets):
//   b_ij fp32 [1152][10]       @ 0         (46080 B)
//   s0/s1/s2 fp32 [128][160]   @ 46080     (3 x 81920 B)
//   xh   bf16 [128][9216]      @ 292096    A-layout [b][k]
//   xl   bf16 [128][9216]      @ 2651392
//   xT   bf16 [9216][128]      @ 5010688   A-layout for k_va ([rc][b])
// Lesson log:
//  R5/R6: in-kernel grid barriers ~20us each -> multi-dispatch.
//  R7/R9 (112.4us): atomic split-K KSPLIT=48 + fused squash/agree; W-lo drop
//    NEUTRAL => k_iter not compute-bound.
//  R8 (152us): doubled TOTAL atomics (1.97M/iter) -> ~+6us/iter. R10 (119.9us):
//    halved per-address contention, same total atomics -> regressed (extra k_va
//    reads). Model: bottleneck = aggregate far-atomic throughput at L2 slices
//    (983K/iter ~ 6-7us). R11: KSPLIT 48->24, NG 5->10 (grid still 240):
//    total atomics halved to 491K/iter, everything else held constant.
// ---------------------------------------------------------------------------

// prep: x -> bf16 hi/lo + transpose; zero b_ij and s0..s2
__global__ __launch_bounds__(256) void k_prep(
    const float* __restrict__ x, unsigned short* __restrict__ xh,
    unsigned short* __restrict__ xl, unsigned short* __restrict__ xT,
    float* __restrict__ b_ij, float* __restrict__ s_all) {
    __shared__ float tile[32][33];
    int bx = blockIdx.x;            // rc tile 0..287
    int by = blockIdx.y;            // b tile 0..3
    int t = threadIdx.x;
    int tx = t & 31, ty = t >> 5;
#pragma unroll
    for (int i = 0; i < 4; i++) {
        int row = ty + i * 8;       // b_local
        size_t idx = (size_t)(by * 32 + row) * KK + bx * 32 + tx;
        float v = x[idx];
        tile[row][tx] = v;
        unsigned short hi = f2bf(v);
        xh[idx] = hi;
        xl[idx] = f2bf(v - bf2f(hi));
    }
    __syncthreads();
#pragma unroll
    for (int i = 0; i < 4; i++) {
        int row = ty + i * 8;       // rc_local
        xT[(size_t)(bx * 32 + row) * B_BATCH + by * 32 + tx] = f2bf(tile[tx][row]);
    }
    int bid = by * 288 + bx;        // 0..1151
    if (bid < 240) s_all[bid * 256 + t] = 0.f;              // 240*256 == 3*20480
    else if (bid < 285) b_ij[(bid - 240) * 256 + t] = 0.f;  // 45*256 == 11520
}

// Fused GEMM iteration: softmax(b_ij) -> c (cap ng only), stage c*W-hi (bf16)
// in LDS, MFMA (ah*bh + al*bh) over this block's 384-k x 16-jd range,
// atomicAdd partials into s (8 atomics/thread; total 491K/iter).
// Grid (24, 10), block 256.
template <bool FIRST>
__global__ __launch_bounds__(256) void k_iter(
    const unsigned short* __restrict__ xh, const unsigned short* __restrict__ xl,
    const float* __restrict__ W, const float* __restrict__ b_ij,
    float* __restrict__ s) {
    __shared__ float cs48[RS];
    __shared__ unsigned short bhs[16][392];   // [jd_l][k_l], 784B rows (16B mult)
    int t = threadIdx.x;
    int ks = blockIdx.x, ng = blockIdx.y;
    int r0 = ks * RS, jd0 = ng * 16;

    if (!FIRST && t < RS) {          // softmax for this block's routes, cap ng
        float bj[N_CAPS], m = -1e30f;
#pragma unroll
        for (int j = 0; j < N_CAPS; j++) { bj[j] = b_ij[(r0 + t) * N_CAPS + j]; m = fmaxf(m, bj[j]); }
        float sum = 0.f;
#pragma unroll
        for (int j = 0; j < N_CAPS; j++) { bj[j] = expf(bj[j] - m); sum += bj[j]; }
        cs48[t] = bj[ng] / sum;
    }
    __syncthreads();

    // stage 48 routes x 16 jd of c*W hi: 768 pairs, 8 fp32 each
#pragma unroll
    for (int p = t; p < RS * 16; p += 256) {
        int rl = p >> 4, jdl = p & 15;
        const float* wp = W + ((size_t)(r0 + rl) * JD + jd0 + jdl) * C_IN;
        float c = FIRST ? 0.1f : cs48[rl];
        short8 vh;
#pragma unroll
        for (int i = 0; i < 8; i++) vh[i] = (short)f2bf(wp[i] * c);
        *(short8*)&bhs[jdl][rl * 8] = vh;    // k_local = rl*8+i
    }
    __syncthreads();

    int w = t >> 6, l = t & 63, row = l & 15, quad = l >> 4;
    const short8* pah0 = (const short8*)(xh + (size_t)(w * 16 + row) * KK + ks * 384);
    const short8* pal0 = (const short8*)(xl + (size_t)(w * 16 + row) * KK + ks * 384);
    const short8* pah1 = (const short8*)(xh + (size_t)((w + 4) * 16 + row) * KK + ks * 384);
    const short8* pal1 = (const short8*)(xl + (size_t)((w + 4) * 16 + row) * KK + ks * 384);
    f32x4 a00 = {0,0,0,0}, a10 = {0,0,0,0};
#pragma unroll
    for (int st = 0; st < 12; st++) {        // K = 384 = 12 steps of 32
        short8 Bh = *(const short8*)&bhs[row][st * 32 + quad * 8];
        short8 Ah0 = pah0[st * 4 + quad], Al0 = pal0[st * 4 + quad];
        short8 Ah1 = pah1[st * 4 + quad], Al1 = pal1[st * 4 + quad];
        a00 = __builtin_amdgcn_mfma_f32_16x16x32_bf16(Ah0, Bh, a00, 0, 0, 0);
        a00 = __builtin_amdgcn_mfma_f32_16x16x32_bf16(Al0, Bh, a00, 0, 0, 0);
        a10 = __builtin_amdgcn_mfma_f32_16x16x32_bf16(Ah1, Bh, a10, 0, 0, 0);
        a10 = __builtin_amdgcn_mfma_f32_16x16x32_bf16(Al1, Bh, a10, 0, 0, 0);
    }
#pragma unroll
    for (int i = 0; i < 4; i++) {            // C/D: col=lane&15 (jd), row=quad*4+i (b)
        int b0 = w * 16 + quad * 4 + i, b1 = b0 + 64;
        atomicAdd(&s[(size_t)b0 * JD + jd0 + row], a00[i]);
        atomicAdd(&s[(size_t)b1 * JD + jd0 + row], a10[i]);
    }
}

// Fused squash + agreement: read s (80KB), squash -> v (bf16) in LDS,
// M2 tile (32 rc x 160 jd) via MFMA, b_ij update. Block owns 4 routes.
__global__ __launch_bounds__(256) void k_va(
    const unsigned short* __restrict__ xT, const float* __restrict__ s,
    const float* __restrict__ W, float* __restrict__ b_ij) {
    __shared__ unsigned short vb[JD][136];   // [jd][b], +8 pad (272B, 16B-mult)
    __shared__ float m2[32][164];            // [rc_local][jd], +4 pad
    int t = threadIdx.x;
    int r0 = blockIdx.x * 4, rc0 = blockIdx.x * 32;

    // squash: 1280 (b,j) pairs, 5 per thread, 16 contiguous floats each
#pragma unroll
    for (int q = 0; q < 5; q++) {
        int pi = t * 5 + q;                  // (b, j) pair
        int b = pi / N_CAPS, j = pi % N_CAPS;
        const float* sp = s + (size_t)b * JD + j * D_DIM;
        float sv[D_DIM], sqn = 0.f;
#pragma unroll
        for (int d = 0; d < D_DIM; d++) { sv[d] = sp[d]; sqn = fmaf(sv[d], sv[d], sqn); }
        float scale = sqn / ((1.f + sqn) * sqrtf(sqn));
#pragma unroll
        for (int d = 0; d < D_DIM; d++)
            vb[j * D_DIM + d][b] = f2bf(sv[d] * scale);
    }
    __syncthreads();

    int w = t >> 6, l = t & 63, row = l & 15, quad = l >> 4;
    for (int u = w; u < 20; u += 4) {        // 2 m-tiles x 10 n-tiles
        int mt = u / 10, nt = u % 10;
        const short8* pa = (const short8*)(xT + (size_t)(rc0 + mt * 16 + row) * B_BATCH);
        f32x4 acc = {0,0,0,0};
#pragma unroll
        for (int st = 0; st < 4; st++) {     // K = 128 = 4 steps of 32
            short8 Bv = *(const short8*)&vb[nt * 16 + row][st * 32 + quad * 8];
            acc = __builtin_amdgcn_mfma_f32_16x16x32_bf16(pa[st * 4 + quad], Bv, acc, 0, 0, 0);
        }
#pragma unroll
        for (int i = 0; i < 4; i++)          // C/D: col=jd, row=rc_local
            m2[mt * 16 + quad * 4 + i][nt * 16 + row] = acc[i];
    }
    __syncthreads();

    for (int p = t; p < 640; p += 256) {     // 4 routes x 160 jd
        int rl = p / JD, jd = p % JD;
        const float* wp = W + ((size_t)(r0 + rl) * JD + jd) * C_IN;
        float a = 0.f;
#pragma unroll
        for (int c = 0; c < C_IN; c++)
            a = fmaf(wp[c], m2[rl * 8 + c][jd], a);
#pragma unroll
        for (int off = 1; off < 16; off <<= 1) a += __shfl_xor(a, off, 16);
        if ((jd & 15) == 0)
            b_ij[(r0 + rl) * N_CAPS + (jd >> 4)] += a * (1.f / B_BATCH);
    }
}

// final: squash s2 -> out
__global__ __launch_bounds__(320) void k_rs_final(
    const float* __restrict__ s, float* __restrict__ out) {
    int t = threadIdx.x;                     // 320 = 2 b x 160 jd
    int bloc = t / JD, jd = t % JD;
    int b = blockIdx.x * 2 + bloc;
    float acc = s[(size_t)b * JD + jd];
    float sq = acc * acc;                    // lane%16 == jd%16 -> width-16 xor
#pragma unroll
    for (int off = 1; off < 16; off <<= 1) sq += __shfl_xor(sq, off, 16);
    float scale = sq / ((1.f + sq) * sqrtf(sq));
    out[(size_t)b * JD + jd] = acc * scale;
}

extern "C" void kernel_launch(void* const* d_in, const int* in_sizes, int n_in,
                              void* d_out, int out_size, void* d_ws, size_t ws_size,
                              hipStream_t stream) {
    const float* x = (const float*)d_in[0];   // [128,1152,8]
    const float* W = (const float*)d_in[1];   // [1,1152,10,16,8]
    float* out = (float*)d_out;               // [128,10,16,1]
    char* ws = (char*)d_ws;

    float*          b_ij = (float*)(ws + 0);
    float*          s0   = (float*)(ws + 46080);
    float*          s1   = (float*)(ws + 46080 + 81920);
    float*          s2   = (float*)(ws + 46080 + 163840);
    unsigned short* xh   = (unsigned short*)(ws + 292096);
    unsigned short* xl   = (unsigned short*)(ws + 2651392);
    unsigned short* xT   = (unsigned short*)(ws + 5010688);

    k_prep<<<dim3(288, 4), 256, 0, stream>>>(x, xh, xl, xT, b_ij, s0);

    k_iter<true><<<dim3(KSPLIT, NG), 256, 0, stream>>>(xh, xl, W, b_ij, s0);
    k_va<<<288, 256, 0, stream>>>(xT, s0, W, b_ij);

    k_iter<false><<<dim3(KSPLIT, NG), 256, 0, stream>>>(xh, xl, W, b_ij, s1);
    k_va<<<288, 256, 0, stream>>>(xT, s1, W, b_ij);

    k_iter<false><<<dim3(KSPLIT, NG), 256, 0, stream>>>(xh, xl, W, b_ij, s2);
    k_rs_final<<<64, 320, 0, stream>>>(s2, out);
}

// Round 12
// 112.162 us; speedup vs baseline: 1.0689x; 1.0276x over previous
//
#include <hip/hip_runtime.h>
#include <math.h>

#define R_ROUTES 1152
#define N_CAPS 10
#define C_IN 8
#define D_DIM 16
#define B_BATCH 128
#define JD 160                      // N_CAPS * D_DIM
#define KK 9216                     // R_ROUTES * C_IN (GEMM K)
#define KSPLIT 48                   // 24 routes = 192 k per split
#define RS 24                       // routes per k-split
#define NG 5                        // jd groups of 32
#define BH 2                        // batch halves (occupancy split)

typedef __attribute__((ext_vector_type(8))) short short8;   // 8 bf16 (4 VGPRs)
typedef __attribute__((ext_vector_type(4))) float f32x4;    // MFMA accumulator

__device__ inline unsigned short f2bf(float f) {            // RNE fp32 -> bf16
    unsigned int u = __float_as_uint(f);
    unsigned int r = u + 0x7FFFu + ((u >> 16) & 1u);
    return (unsigned short)(r >> 16);
}
__device__ inline float bf2f(unsigned short h) {
    return __uint_as_float(((unsigned int)h) << 16);
}

// ---------------------------------------------------------------------------
// ws layout (byte offsets):
//   b_ij fp32 [1152][10]       @ 0         (46080 B)
//   s0/s1/s2 fp32 [128][160]   @ 46080     (3 x 81920 B)
//   xh   bf16 [128][9216]      @ 292096    A-layout [b][k]
//   xl   bf16 [128][9216]      @ 2651392
//   xT   bf16 [9216][128]      @ 5010688   A-layout for k_va ([rc][b])
// Lesson log:
//  R5/R6: in-kernel grid barriers ~20us each -> multi-dispatch.
//  R7/R9 (112.4us): atomic split-K KSPLIT=48 + fused squash/agree.
//  R9: W-lo MFMA drop NEUTRAL -> k_iter not compute-bound.
//  R10 (shadow, same total atomics): REGRESSED. R11 (half total atomics):
//    NEUTRAL -> atomic throughput exonerated.
//  Current model: grid 240 = 4 waves/CU = 12.5% occupancy -> latency-bound.
//  R12: k_iter batch-split (grid 48x5x2, 64 b/block) -> 1920 waves (~7.5/CU),
//    all work totals unchanged except W staged 2x (proven non-critical).
// ---------------------------------------------------------------------------

// prep: x -> bf16 hi/lo + transpose; zero b_ij and s0..s2
__global__ __launch_bounds__(256) void k_prep(
    const float* __restrict__ x, unsigned short* __restrict__ xh,
    unsigned short* __restrict__ xl, unsigned short* __restrict__ xT,
    float* __restrict__ b_ij, float* __restrict__ s_all) {
    __shared__ float tile[32][33];
    int bx = blockIdx.x;            // rc tile 0..287
    int by = blockIdx.y;            // b tile 0..3
    int t = threadIdx.x;
    int tx = t & 31, ty = t >> 5;
#pragma unroll
    for (int i = 0; i < 4; i++) {
        int row = ty + i * 8;       // b_local
        size_t idx = (size_t)(by * 32 + row) * KK + bx * 32 + tx;
        float v = x[idx];
        tile[row][tx] = v;
        unsigned short hi = f2bf(v);
        xh[idx] = hi;
        xl[idx] = f2bf(v - bf2f(hi));
    }
    __syncthreads();
#pragma unroll
    for (int i = 0; i < 4; i++) {
        int row = ty + i * 8;       // rc_local
        xT[(size_t)(bx * 32 + row) * B_BATCH + by * 32 + tx] = f2bf(tile[tx][row]);
    }
    int bid = by * 288 + bx;        // 0..1151
    if (bid < 240) s_all[bid * 256 + t] = 0.f;              // 240*256 == 3*20480
    else if (bid < 285) b_ij[(bid - 240) * 256 + t] = 0.f;  // 45*256 == 11520
}

// Fused GEMM iteration: softmax(b_ij) -> c, stage c*W-hi (bf16) in LDS,
// MFMA (ah*bh + al*bh) over this block's 192-k x 32-jd x 64-b range,
// atomicAdd partials into s. Grid (48, 5, 2), block 256 (4 m-tiles/block,
// one per wave) -> 1920 waves total for latency hiding.
template <bool FIRST>
__global__ __launch_bounds__(256) void k_iter(
    const unsigned short* __restrict__ xh, const unsigned short* __restrict__ xl,
    const float* __restrict__ W, const float* __restrict__ b_ij,
    float* __restrict__ s) {
    __shared__ float cs[RS][N_CAPS];
    __shared__ unsigned short bhs[32][200];   // [jd_l][k_l], 400B rows (16B mult)
    int t = threadIdx.x;
    int ks = blockIdx.x, ng = blockIdx.y, bh = blockIdx.z;
    int r0 = ks * RS, jd0 = ng * 32, b_base = bh * 64;

    if (!FIRST && t < RS) {          // softmax for this block's routes
        float bj[N_CAPS], m = -1e30f;
#pragma unroll
        for (int j = 0; j < N_CAPS; j++) { bj[j] = b_ij[(r0 + t) * N_CAPS + j]; m = fmaxf(m, bj[j]); }
        float sum = 0.f;
#pragma unroll
        for (int j = 0; j < N_CAPS; j++) { bj[j] = expf(bj[j] - m); sum += bj[j]; }
        float inv = 1.f / sum;
#pragma unroll
        for (int j = 0; j < N_CAPS; j++) cs[t][j] = bj[j] * inv;
    }
    __syncthreads();

    // stage 24 routes x 32 jd of c*W hi: 768 pairs, 8 fp32 each
#pragma unroll
    for (int p = t; p < RS * 32; p += 256) {
        int rl = p >> 5, jdl = p & 31;
        const float* wp = W + ((size_t)(r0 + rl) * JD + jd0 + jdl) * C_IN;
        float c = FIRST ? 0.1f : cs[rl][(jd0 + jdl) >> 4];
        short8 vh;
#pragma unroll
        for (int i = 0; i < 8; i++) vh[i] = (short)f2bf(wp[i] * c);
        *(short8*)&bhs[jdl][rl * 8] = vh;    // k_local = rl*8+i
    }
    __syncthreads();

    int w = t >> 6, l = t & 63, row = l & 15, quad = l >> 4;
    // wave w owns m-tile w: batch rows b_base + w*16 .. +16
    const short8* pah = (const short8*)(xh + (size_t)(b_base + w * 16 + row) * KK + ks * 192);
    const short8* pal = (const short8*)(xl + (size_t)(b_base + w * 16 + row) * KK + ks * 192);
    f32x4 acc0 = {0,0,0,0}, acc1 = {0,0,0,0};
#pragma unroll
    for (int st = 0; st < 6; st++) {         // K = 192 = 6 steps of 32
        short8 Bh0 = *(const short8*)&bhs[row][st * 32 + quad * 8];
        short8 Bh1 = *(const short8*)&bhs[16 + row][st * 32 + quad * 8];
        short8 Ah = pah[st * 4 + quad], Al = pal[st * 4 + quad];
        acc0 = __builtin_amdgcn_mfma_f32_16x16x32_bf16(Ah, Bh0, acc0, 0, 0, 0);
        acc0 = __builtin_amdgcn_mfma_f32_16x16x32_bf16(Al, Bh0, acc0, 0, 0, 0);
        acc1 = __builtin_amdgcn_mfma_f32_16x16x32_bf16(Ah, Bh1, acc1, 0, 0, 0);
        acc1 = __builtin_amdgcn_mfma_f32_16x16x32_bf16(Al, Bh1, acc1, 0, 0, 0);
    }
#pragma unroll
    for (int i = 0; i < 4; i++) {            // C/D: col=lane&15 (jd), row=quad*4+i (b)
        int b0 = b_base + w * 16 + quad * 4 + i;
        atomicAdd(&s[(size_t)b0 * JD + jd0 + row],      acc0[i]);
        atomicAdd(&s[(size_t)b0 * JD + jd0 + 16 + row], acc1[i]);
    }
}

// Fused squash + agreement: read s (80KB), squash -> v (bf16) in LDS,
// M2 tile (32 rc x 160 jd) via MFMA, b_ij update. Block owns 4 routes.
__global__ __launch_bounds__(256) void k_va(
    const unsigned short* __restrict__ xT, const float* __restrict__ s,
    const float* __restrict__ W, float* __restrict__ b_ij) {
    __shared__ unsigned short vb[JD][136];   // [jd][b], +8 pad (272B, 16B-mult)
    __shared__ float m2[32][164];            // [rc_local][jd], +4 pad
    int t = threadIdx.x;
    int r0 = blockIdx.x * 4, rc0 = blockIdx.x * 32;

    // squash: 1280 (b,j) pairs, 5 per thread, 16 contiguous floats each
#pragma unroll
    for (int q = 0; q < 5; q++) {
        int pi = t * 5 + q;                  // (b, j) pair
        int b = pi / N_CAPS, j = pi % N_CAPS;
        const float* sp = s + (size_t)b * JD + j * D_DIM;
        float sv[D_DIM], sqn = 0.f;
#pragma unroll
        for (int d = 0; d < D_DIM; d++) { sv[d] = sp[d]; sqn = fmaf(sv[d], sv[d], sqn); }
        float scale = sqn / ((1.f + sqn) * sqrtf(sqn));
#pragma unroll
        for (int d = 0; d < D_DIM; d++)
            vb[j * D_DIM + d][b] = f2bf(sv[d] * scale);
    }
    __syncthreads();

    int w = t >> 6, l = t & 63, row = l & 15, quad = l >> 4;
    for (int u = w; u < 20; u += 4) {        // 2 m-tiles x 10 n-tiles
        int mt = u / 10, nt = u % 10;
        const short8* pa = (const short8*)(xT + (size_t)(rc0 + mt * 16 + row) * B_BATCH);
        f32x4 acc = {0,0,0,0};
#pragma unroll
        for (int st = 0; st < 4; st++) {     // K = 128 = 4 steps of 32
            short8 Bv = *(const short8*)&vb[nt * 16 + row][st * 32 + quad * 8];
            acc = __builtin_amdgcn_mfma_f32_16x16x32_bf16(pa[st * 4 + quad], Bv, acc, 0, 0, 0);
        }
#pragma unroll
        for (int i = 0; i < 4; i++)          // C/D: col=jd, row=rc_local
            m2[mt * 16 + quad * 4 + i][nt * 16 + row] = acc[i];
    }
    __syncthreads();

    for (int p = t; p < 640; p += 256) {     // 4 routes x 160 jd
        int rl = p / JD, jd = p % JD;
        const float* wp = W + ((size_t)(r0 + rl) * JD + jd) * C_IN;
        float a = 0.f;
#pragma unroll
        for (int c = 0; c < C_IN; c++)
            a = fmaf(wp[c], m2[rl * 8 + c][jd], a);
#pragma unroll
        for (int off = 1; off < 16; off <<= 1) a += __shfl_xor(a, off, 16);
        if ((jd & 15) == 0)
            b_ij[(r0 + rl) * N_CAPS + (jd >> 4)] += a * (1.f / B_BATCH);
    }
}

// final: squash s2 -> out
__global__ __launch_bounds__(320) void k_rs_final(
    const float* __restrict__ s, float* __restrict__ out) {
    int t = threadIdx.x;                     // 320 = 2 b x 160 jd
    int bloc = t / JD, jd = t % JD;
    int b = blockIdx.x * 2 + bloc;
    float acc = s[(size_t)b * JD + jd];
    float sq = acc * acc;                    // lane%16 == jd%16 -> width-16 xor
#pragma unroll
    for (int off = 1; off < 16; off <<= 1) sq += __shfl_xor(sq, off, 16);
    float scale = sq / ((1.f + sq) * sqrtf(sq));
    out[(size_t)b * JD + jd] = acc * scale;
}

extern "C" void kernel_launch(void* const* d_in, const int* in_sizes, int n_in,
                              void* d_out, int out_size, void* d_ws, size_t ws_size,
                              hipStream_t stream) {
    const float* x = (const float*)d_in[0];   // [128,1152,8]
    const float* W = (const float*)d_in[1];   // [1,1152,10,16,8]
    float* out = (float*)d_out;               // [128,10,16,1]
    char* ws = (char*)d_ws;

    float*          b_ij = (float*)(ws + 0);
    float*          s0   = (float*)(ws + 46080);
    float*          s1   = (float*)(ws + 46080 + 81920);
    float*          s2   = (float*)(ws + 46080 + 163840);
    unsigned short* xh   = (unsigned short*)(ws + 292096);
    unsigned short* xl   = (unsigned short*)(ws + 2651392);
    unsigned short* xT   = (unsigned short*)(ws + 5010688);

    k_prep<<<dim3(288, 4), 256, 0, stream>>>(x, xh, xl, xT, b_ij, s0);

    k_iter<true><<<dim3(KSPLIT, NG, BH), 256, 0, stream>>>(xh, xl, W, b_ij, s0);
    k_va<<<288, 256, 0, stream>>>(xT, s0, W, b_ij);

    k_iter<false><<<dim3(KSPLIT, NG, BH), 256, 0, stream>>>(xh, xl, W, b_ij, s1);
    k_va<<<288, 256, 0, stream>>>(xT, s1, W, b_ij);

    k_iter<false><<<dim3(KSPLIT, NG, BH), 256, 0, stream>>>(xh, xl, W, b_ij, s2);
    k_rs_final<<<64, 320, 0, stream>>>(s2, out);
}